// Round 2
// baseline (255.196 us; speedup 1.0000x reference)
//
#include <hip/hip_runtime.h>
#include <math.h>

// Problem constants (from reference setup_inputs)
constexpr int NB = 16;          // batches
constexpr int XY = 512 * 512;   // pixels per image
constexpr int NV = XY / 4;      // float4 vectors per image
constexpr int G  = 128;         // blocks per batch (COMPILE-TIME: trip count = NV/(G*256) = 2)

// Workspace layout (all written before read => no memset, poison-safe):
//   bytes [0..135]   : double llsum[16], double final_sum   (zeroed by pass1 blk(0,0))
//   bytes [136..203] : int arrive[16], int batches_done     (zeroed by pass1 blk(0,0))
//   bytes [512.. ]   : float partial1[NB][G][32]  (29 used) ~256 KB
constexpr int P1OFF = 512;

__device__ __forceinline__ float waveReduce64(float v) {
#pragma unroll
    for (int off = 32; off > 0; off >>= 1) v += __shfl_down(v, off, 64);
    return v;
}

// Coerce a block-uniform float into an SGPR (frees VGPRs in the phase-C loop).
__device__ __forceinline__ float rfl(float x) {
    return __uint_as_float(__builtin_amdgcn_readfirstlane(__float_as_uint(x)));
}

// Straight-line per-pixel moment accumulation. All accumulators are NAMED
// SCALARS — no arrays, no lambdas (array version spilled to scratch).
#define PIX1(h_, e0_, e1_, e2_, p0_, p1_, p2_, p3_) do {                      \
    float mm_ = ((h_) == 1) ? 1.f : 0.f;                                      \
    cnt += mm_;                                                               \
    float w0_ = (p0_) * mm_, w1_ = (p1_) * mm_, w2_ = (p2_) * mm_,            \
          w3_ = (p3_) * mm_;                                                  \
    s0_0 += w0_; s0_1 += w1_; s0_2 += w2_; s0_3 += w3_;                       \
    float t_;                                                                 \
    t_ = w0_ * (e0_); u00 += t_; q00 = fmaf(t_, (e0_), q00);                  \
    t_ = w0_ * (e1_); u01 += t_; q01 = fmaf(t_, (e1_), q01);                  \
    t_ = w0_ * (e2_); u02 += t_; q02 = fmaf(t_, (e2_), q02);                  \
    t_ = w1_ * (e0_); u10 += t_; q10 = fmaf(t_, (e0_), q10);                  \
    t_ = w1_ * (e1_); u11 += t_; q11 = fmaf(t_, (e1_), q11);                  \
    t_ = w1_ * (e2_); u12 += t_; q12 = fmaf(t_, (e2_), q12);                  \
    t_ = w2_ * (e0_); u20 += t_; q20 = fmaf(t_, (e0_), q20);                  \
    t_ = w2_ * (e1_); u21 += t_; q21 = fmaf(t_, (e1_), q21);                  \
    t_ = w2_ * (e2_); u22 += t_; q22 = fmaf(t_, (e2_), q22);                  \
    t_ = w3_ * (e0_); u30 += t_; q30 = fmaf(t_, (e0_), q30);                  \
    t_ = w3_ * (e1_); u31 += t_; q31 = fmaf(t_, (e1_), q31);                  \
    t_ = w3_ * (e2_); u32 += t_; q32 = fmaf(t_, (e2_), q32);                  \
} while (0)

#define RED(i_, var_) { float r_ = waveReduce64(var_); if (lane == 0) sh[wav][i_] = r_; }

// Per-component parameter reconstruction (block-uniform, f64 for the
// cancellation in S2 - 2 mu S1 + mu^2 S0). Reads the `tot` LDS array.
#define PARAMK(K_, mu0_, mu1_, mu2_, h0_, h1_, h2_, C_) {                     \
    double S0_ = tot[1 + (K_)];                                               \
    double den_ = S0_ + 1e-10;                                                \
    double Cd_ = 1.0;                                                         \
    double S1_, S2_, muv_, var_;                                              \
    S1_ = tot[5 + (K_)*3 + 0]; S2_ = tot[17 + (K_)*3 + 0];                    \
    muv_ = S1_ / den_;                                                        \
    var_ = (S2_ - 2.0 * muv_ * S1_ + muv_ * muv_ * S0_) / den_ + 1e-10;       \
    mu0_ = (float)muv_; h0_ = (float)(0.5 / var_);                            \
    Cd_ *= 1.0 / sqrt(6.283185307179586 * var_);                              \
    S1_ = tot[5 + (K_)*3 + 1]; S2_ = tot[17 + (K_)*3 + 1];                    \
    muv_ = S1_ / den_;                                                        \
    var_ = (S2_ - 2.0 * muv_ * S1_ + muv_ * muv_ * S0_) / den_ + 1e-10;       \
    mu1_ = (float)muv_; h1_ = (float)(0.5 / var_);                            \
    Cd_ *= 1.0 / sqrt(6.283185307179586 * var_);                              \
    S1_ = tot[5 + (K_)*3 + 2]; S2_ = tot[17 + (K_)*3 + 2];                    \
    muv_ = S1_ / den_;                                                        \
    var_ = (S2_ - 2.0 * muv_ * S1_ + muv_ * muv_ * S0_) / den_ + 1e-10;       \
    mu2_ = (float)muv_; h2_ = (float)(0.5 / var_);                            \
    Cd_ *= 1.0 / sqrt(6.283185307179586 * var_);                              \
    C_ = (float)Cd_;                                                          \
}

#define PIX2(h_, e0_, e1_, e2_, p0_, p1_, p2_, p3_) do {                      \
    float m_ = ((h_) == 1) ? 1.f : 0.f;                                       \
    float d0_, d1_, d2_, ex_, pc_;                                            \
    float mix_;                                                               \
    d0_ = (e0_) - mu00; d1_ = (e1_) - mu01; d2_ = (e2_) - mu02;               \
    ex_ = fmaf(d0_ * d0_, hv00, fmaf(d1_ * d1_, hv01, d2_ * d2_ * hv02));     \
    pc_ = (p0_) * (p0_) * (p0_);                                              \
    mix_ = C0 * pc_ * __expf(-ex_);                                           \
    d0_ = (e0_) - mu10; d1_ = (e1_) - mu11; d2_ = (e2_) - mu12;               \
    ex_ = fmaf(d0_ * d0_, hv10, fmaf(d1_ * d1_, hv11, d2_ * d2_ * hv12));     \
    pc_ = (p1_) * (p1_) * (p1_);                                              \
    mix_ = fmaf(C1 * pc_, __expf(-ex_), mix_);                                \
    d0_ = (e0_) - mu20; d1_ = (e1_) - mu21; d2_ = (e2_) - mu22;               \
    ex_ = fmaf(d0_ * d0_, hv20, fmaf(d1_ * d1_, hv21, d2_ * d2_ * hv22));     \
    pc_ = (p2_) * (p2_) * (p2_);                                              \
    mix_ = fmaf(C2 * pc_, __expf(-ex_), mix_);                                \
    d0_ = (e0_) - mu30; d1_ = (e1_) - mu31; d2_ = (e2_) - mu32;               \
    ex_ = fmaf(d0_ * d0_, hv30, fmaf(d1_ * d1_, hv31, d2_ * d2_ * hv32));     \
    pc_ = (p3_) * (p3_) * (p3_);                                              \
    mix_ = fmaf(C3 * pc_, __expf(-ex_), mix_);                                \
    lacc += m_ * __logf(mix_ + 1e-10f);                                       \
} while (0)

// ---------------------------------------------------------------------------
// Pass 1: weighted moments -> per-block partials (no atomics, no memset).
// Grid (G, NB) = (128, 16) = 2048 blocks; NIT=2 fully unrolled so up to 18
// dwordx4 loads can be in flight per thread (round-0 VGPR=44 serialized them).
// ---------------------------------------------------------------------------
__global__ __launch_bounds__(256) void pass1_moments(
        const float* __restrict__ predictions,
        const float* __restrict__ inputs,
        const int*   __restrict__ heart,
        char*        __restrict__ wsraw) {
    const int b   = blockIdx.y;
    const int g   = blockIdx.x;
    const int tid = threadIdx.x;

    const float4* P1 = reinterpret_cast<const float4*>(predictions + (size_t)b * 5 * XY + 1 * XY);
    const float4* P2 = reinterpret_cast<const float4*>(predictions + (size_t)b * 5 * XY + 2 * XY);
    const float4* P3 = reinterpret_cast<const float4*>(predictions + (size_t)b * 5 * XY + 3 * XY);
    const float4* P4 = reinterpret_cast<const float4*>(predictions + (size_t)b * 5 * XY + 4 * XY);
    const float4* I0 = reinterpret_cast<const float4*>(inputs + (size_t)b * 3 * XY + 0 * XY);
    const float4* I1 = reinterpret_cast<const float4*>(inputs + (size_t)b * 3 * XY + 1 * XY);
    const float4* I2 = reinterpret_cast<const float4*>(inputs + (size_t)b * 3 * XY + 2 * XY);
    const int4*   H  = reinterpret_cast<const int4*>(heart + (size_t)b * XY);

    float cnt = 0.f;
    float s0_0 = 0.f, s0_1 = 0.f, s0_2 = 0.f, s0_3 = 0.f;
    float u00 = 0.f, u01 = 0.f, u02 = 0.f, u10 = 0.f, u11 = 0.f, u12 = 0.f;
    float u20 = 0.f, u21 = 0.f, u22 = 0.f, u30 = 0.f, u31 = 0.f, u32 = 0.f;
    float q00 = 0.f, q01 = 0.f, q02 = 0.f, q10 = 0.f, q11 = 0.f, q12 = 0.f;
    float q20 = 0.f, q21 = 0.f, q22 = 0.f, q30 = 0.f, q31 = 0.f, q32 = 0.f;

    const int base0 = g * 256 + tid;
    constexpr int STRIDE = G * 256;       // 32768
    constexpr int NIT = NV / STRIDE;      // 2, compile-time -> full unroll

#pragma unroll
    for (int it = 0; it < NIT; ++it) {
        const int v = base0 + it * STRIDE;
        int4   h  = H[v];
        float4 f0 = I0[v], f1 = I1[v], f2 = I2[v];
        float4 g0 = P1[v], g1 = P2[v], g2 = P3[v], g3 = P4[v];
        PIX1(h.x, f0.x, f1.x, f2.x, g0.x, g1.x, g2.x, g3.x);
        PIX1(h.y, f0.y, f1.y, f2.y, g0.y, g1.y, g2.y, g3.y);
        PIX1(h.z, f0.z, f1.z, f2.z, g0.z, g1.z, g2.z, g3.z);
        PIX1(h.w, f0.w, f1.w, f2.w, g0.w, g1.w, g2.w, g3.w);
    }

    __shared__ float sh[4][29];
    const int lane = tid & 63;
    const int wav  = tid >> 6;
    RED(0, cnt);
    RED(1, s0_0); RED(2, s0_1); RED(3, s0_2); RED(4, s0_3);
    RED(5, u00); RED(6, u01); RED(7, u02);
    RED(8, u10); RED(9, u11); RED(10, u12);
    RED(11, u20); RED(12, u21); RED(13, u22);
    RED(14, u30); RED(15, u31); RED(16, u32);
    RED(17, q00); RED(18, q01); RED(19, q02);
    RED(20, q10); RED(21, q11); RED(22, q12);
    RED(23, q20); RED(24, q21); RED(25, q22);
    RED(26, q30); RED(27, q31); RED(28, q32);
    __syncthreads();

    float* p1 = reinterpret_cast<float*>(wsraw + P1OFF);
    if (tid < 29) {
        float v = sh[0][tid] + sh[1][tid] + sh[2][tid] + sh[3][tid];
        p1[(((size_t)b * G + g) << 5) + tid] = v;   // per-block partial
    }

    // Zero the pass2 control state (ordered before pass2 by the graph edge).
    if (b == 0 && g == 0) {
        double* wsd = reinterpret_cast<double*>(wsraw);
        if (tid < 17) wsd[tid] = 0.0;                 // llsum[16] + final_sum
        int* wsi = reinterpret_cast<int*>(wsd + 17);
        if (tid >= 32 && tid < 49) wsi[tid - 32] = 0; // arrive[16] + batches_done
    }
}

// ---------------------------------------------------------------------------
// Pass 2: batch totals (from partials) -> params -> loglik -> fused finalize.
// Finalize uses ONLY device-scope atomic RMWs for cross-block communication.
// ---------------------------------------------------------------------------
__global__ __launch_bounds__(256) void pass2_loglik(
        const float* __restrict__ predictions,
        const float* __restrict__ inputs,
        const int*   __restrict__ heart,
        float*       __restrict__ out,
        char*        __restrict__ wsraw) {
    const int b   = blockIdx.y;
    const int g   = blockIdx.x;
    const int tid = threadIdx.x;

    // ---- batch totals from pass1 partials (written in previous dispatch) ----
    __shared__ double tot[29];
    {
        const float* p1 = reinterpret_cast<const float*>(wsraw + P1OFF);
        if (tid < 29) {
            const float* basep = p1 + ((size_t)b * G << 5) + tid;
            double s = 0.0;
#pragma unroll 8
            for (int j = 0; j < G; ++j) s += (double)basep[(size_t)j << 5];
            tot[tid] = s;
        }
    }
    __syncthreads();

    float mu00, mu01, mu02, mu10, mu11, mu12, mu20, mu21, mu22, mu30, mu31, mu32;
    float hv00, hv01, hv02, hv10, hv11, hv12, hv20, hv21, hv22, hv30, hv31, hv32;
    float C0, C1, C2, C3;
    PARAMK(0, mu00, mu01, mu02, hv00, hv01, hv02, C0);
    PARAMK(1, mu10, mu11, mu12, hv10, hv11, hv12, C1);
    PARAMK(2, mu20, mu21, mu22, hv20, hv21, hv22, C2);
    PARAMK(3, mu30, mu31, mu32, hv30, hv31, hv32, C3);
    // Block-uniform -> SGPRs (each PIX2 use is a single-SGPR VALU operand).
    mu00=rfl(mu00); mu01=rfl(mu01); mu02=rfl(mu02);
    mu10=rfl(mu10); mu11=rfl(mu11); mu12=rfl(mu12);
    mu20=rfl(mu20); mu21=rfl(mu21); mu22=rfl(mu22);
    mu30=rfl(mu30); mu31=rfl(mu31); mu32=rfl(mu32);
    hv00=rfl(hv00); hv01=rfl(hv01); hv02=rfl(hv02);
    hv10=rfl(hv10); hv11=rfl(hv11); hv12=rfl(hv12);
    hv20=rfl(hv20); hv21=rfl(hv21); hv22=rfl(hv22);
    hv30=rfl(hv30); hv31=rfl(hv31); hv32=rfl(hv32);
    C0=rfl(C0); C1=rfl(C1); C2=rfl(C2); C3=rfl(C3);

    const float4* P1 = reinterpret_cast<const float4*>(predictions + (size_t)b * 5 * XY + 1 * XY);
    const float4* P2 = reinterpret_cast<const float4*>(predictions + (size_t)b * 5 * XY + 2 * XY);
    const float4* P3 = reinterpret_cast<const float4*>(predictions + (size_t)b * 5 * XY + 3 * XY);
    const float4* P4 = reinterpret_cast<const float4*>(predictions + (size_t)b * 5 * XY + 4 * XY);
    const float4* I0 = reinterpret_cast<const float4*>(inputs + (size_t)b * 3 * XY + 0 * XY);
    const float4* I1 = reinterpret_cast<const float4*>(inputs + (size_t)b * 3 * XY + 1 * XY);
    const float4* I2 = reinterpret_cast<const float4*>(inputs + (size_t)b * 3 * XY + 2 * XY);
    const int4*   H  = reinterpret_cast<const int4*>(heart + (size_t)b * XY);

    float lacc = 0.f;
    const int base0 = g * 256 + tid;
    constexpr int STRIDE = G * 256;       // 32768
    constexpr int NIT = NV / STRIDE;      // 2

#pragma unroll
    for (int it = 0; it < NIT; ++it) {
        const int v = base0 + it * STRIDE;
        int4   h  = H[v];
        float4 f0 = I0[v], f1 = I1[v], f2 = I2[v];
        float4 g0 = P1[v], g1 = P2[v], g2 = P3[v], g3 = P4[v];
        PIX2(h.x, f0.x, f1.x, f2.x, g0.x, g1.x, g2.x, g3.x);
        PIX2(h.y, f0.y, f1.y, f2.y, g0.y, g1.y, g2.y, g3.y);
        PIX2(h.z, f0.z, f1.z, f2.z, g0.z, g1.z, g2.z, g3.z);
        PIX2(h.w, f0.w, f1.w, f2.w, g0.w, g1.w, g2.w, g3.w);
    }

    __shared__ float sh2[4];
    const int lane = tid & 63;
    const int wav  = tid >> 6;
    {
        float v = waveReduce64(lacc);
        if (lane == 0) sh2[wav] = v;
    }
    __syncthreads();

    if (tid == 0) {
        double* llsum        = reinterpret_cast<double*>(wsraw);
        double* final_sum    = llsum + 16;
        int*    arrive       = reinterpret_cast<int*>(llsum + 17);
        int*    batches_done = arrive + 16;

        float t = sh2[0] + sh2[1] + sh2[2] + sh2[3];
        atomicAdd(&llsum[b], (double)t);
        __threadfence();
        int prev = atomicAdd(&arrive[b], 1);
        if (prev == G - 1) {                       // last block of batch b
            double ll  = atomicAdd(&llsum[b], 0.0);    // coherent read
            double bval = -ll / tot[0];                // tot[0] = mask count
            atomicAdd(final_sum, bval * (1.0 / (double)NB));
            __threadfence();
            int bprev = atomicAdd(batches_done, 1);
            if (bprev == NB - 1) {                 // very last batch
                double fs = atomicAdd(final_sum, 0.0); // coherent read
                out[0] = (float)fs;
            }
        }
    }
}

extern "C" void kernel_launch(void* const* d_in, const int* in_sizes, int n_in,
                              void* d_out, int out_size, void* d_ws, size_t ws_size,
                              hipStream_t stream) {
    const float* predictions = (const float*)d_in[0];
    const float* inputs      = (const float*)d_in[1];
    const int*   heart       = (const int*)d_in[2];
    float* out   = (float*)d_out;
    char*  wsraw = (char*)d_ws;

    // No memset, no finalize dispatch: 2 nodes total.
    pass1_moments<<<dim3(G, NB), 256, 0, stream>>>(predictions, inputs, heart, wsraw);
    pass2_loglik <<<dim3(G, NB), 256, 0, stream>>>(predictions, inputs, heart, out, wsraw);
}

// Round 3
// 202.281 us; speedup vs baseline: 1.2616x; 1.2616x over previous
//
#include <hip/hip_runtime.h>
#include <math.h>

// Problem constants (from reference setup_inputs)
constexpr int NB = 16;          // batches
constexpr int XY = 512 * 512;   // pixels per image
constexpr int NV = XY / 4;      // float4 vectors per image
constexpr int G  = 128;         // blocks per batch; NIT = NV/(G*256) = 2 (compile-time)

// Workspace layout (every location written before read => no memset, no atomics,
// poison-safe):
//   bytes [0    .. 4095]   : double tot[NB][32]          (29 used; reduce_totals)
//   bytes [4096 .. +256K]  : float  partial1[NB][G][32]  (slots 0..28 = pass1 moments,
//                                                         slot 29 = pass2 loglik partial)
constexpr int P1OFF = 4096;

__device__ __forceinline__ float waveReduce64(float v) {
#pragma unroll
    for (int off = 32; off > 0; off >>= 1) v += __shfl_down(v, off, 64);
    return v;
}

// Coerce a block-uniform float into an SGPR (frees VGPRs in the pass2 loop).
__device__ __forceinline__ float rfl(float x) {
    return __uint_as_float(__builtin_amdgcn_readfirstlane(__float_as_uint(x)));
}

// Straight-line per-pixel moment accumulation. All accumulators are NAMED
// SCALARS — no arrays, no lambdas (array version spilled to scratch).
#define PIX1(h_, e0_, e1_, e2_, p0_, p1_, p2_, p3_) do {                      \
    float mm_ = ((h_) == 1) ? 1.f : 0.f;                                      \
    cnt += mm_;                                                               \
    float w0_ = (p0_) * mm_, w1_ = (p1_) * mm_, w2_ = (p2_) * mm_,            \
          w3_ = (p3_) * mm_;                                                  \
    s0_0 += w0_; s0_1 += w1_; s0_2 += w2_; s0_3 += w3_;                       \
    float t_;                                                                 \
    t_ = w0_ * (e0_); u00 += t_; q00 = fmaf(t_, (e0_), q00);                  \
    t_ = w0_ * (e1_); u01 += t_; q01 = fmaf(t_, (e1_), q01);                  \
    t_ = w0_ * (e2_); u02 += t_; q02 = fmaf(t_, (e2_), q02);                  \
    t_ = w1_ * (e0_); u10 += t_; q10 = fmaf(t_, (e0_), q10);                  \
    t_ = w1_ * (e1_); u11 += t_; q11 = fmaf(t_, (e1_), q11);                  \
    t_ = w1_ * (e2_); u12 += t_; q12 = fmaf(t_, (e2_), q12);                  \
    t_ = w2_ * (e0_); u20 += t_; q20 = fmaf(t_, (e0_), q20);                  \
    t_ = w2_ * (e1_); u21 += t_; q21 = fmaf(t_, (e1_), q21);                  \
    t_ = w2_ * (e2_); u22 += t_; q22 = fmaf(t_, (e2_), q22);                  \
    t_ = w3_ * (e0_); u30 += t_; q30 = fmaf(t_, (e0_), q30);                  \
    t_ = w3_ * (e1_); u31 += t_; q31 = fmaf(t_, (e1_), q31);                  \
    t_ = w3_ * (e2_); u32 += t_; q32 = fmaf(t_, (e2_), q32);                  \
} while (0)

#define RED(i_, var_) { float r_ = waveReduce64(var_); if (lane == 0) sh[wav][i_] = r_; }

// Per-component parameter reconstruction (block-uniform, f64 for the
// cancellation in S2 - 2 mu S1 + mu^2 S0). Reads the precomputed `tot` doubles.
#define PARAMK(K_, mu0_, mu1_, mu2_, h0_, h1_, h2_, C_) {                     \
    double S0_ = tot[1 + (K_)];                                               \
    double den_ = S0_ + 1e-10;                                                \
    double Cd_ = 1.0;                                                         \
    double S1_, S2_, muv_, var_;                                              \
    S1_ = tot[5 + (K_)*3 + 0]; S2_ = tot[17 + (K_)*3 + 0];                    \
    muv_ = S1_ / den_;                                                        \
    var_ = (S2_ - 2.0 * muv_ * S1_ + muv_ * muv_ * S0_) / den_ + 1e-10;       \
    mu0_ = (float)muv_; h0_ = (float)(0.5 / var_);                            \
    Cd_ *= 1.0 / sqrt(6.283185307179586 * var_);                              \
    S1_ = tot[5 + (K_)*3 + 1]; S2_ = tot[17 + (K_)*3 + 1];                    \
    muv_ = S1_ / den_;                                                        \
    var_ = (S2_ - 2.0 * muv_ * S1_ + muv_ * muv_ * S0_) / den_ + 1e-10;       \
    mu1_ = (float)muv_; h1_ = (float)(0.5 / var_);                            \
    Cd_ *= 1.0 / sqrt(6.283185307179586 * var_);                              \
    S1_ = tot[5 + (K_)*3 + 2]; S2_ = tot[17 + (K_)*3 + 2];                    \
    muv_ = S1_ / den_;                                                        \
    var_ = (S2_ - 2.0 * muv_ * S1_ + muv_ * muv_ * S0_) / den_ + 1e-10;       \
    mu2_ = (float)muv_; h2_ = (float)(0.5 / var_);                            \
    Cd_ *= 1.0 / sqrt(6.283185307179586 * var_);                              \
    C_ = (float)Cd_;                                                          \
}

#define PIX2(h_, e0_, e1_, e2_, p0_, p1_, p2_, p3_) do {                      \
    float m_ = ((h_) == 1) ? 1.f : 0.f;                                       \
    float d0_, d1_, d2_, ex_, pc_;                                            \
    float mix_;                                                               \
    d0_ = (e0_) - mu00; d1_ = (e1_) - mu01; d2_ = (e2_) - mu02;               \
    ex_ = fmaf(d0_ * d0_, hv00, fmaf(d1_ * d1_, hv01, d2_ * d2_ * hv02));     \
    pc_ = (p0_) * (p0_) * (p0_);                                              \
    mix_ = C0 * pc_ * __expf(-ex_);                                           \
    d0_ = (e0_) - mu10; d1_ = (e1_) - mu11; d2_ = (e2_) - mu12;               \
    ex_ = fmaf(d0_ * d0_, hv10, fmaf(d1_ * d1_, hv11, d2_ * d2_ * hv12));     \
    pc_ = (p1_) * (p1_) * (p1_);                                              \
    mix_ = fmaf(C1 * pc_, __expf(-ex_), mix_);                                \
    d0_ = (e0_) - mu20; d1_ = (e1_) - mu21; d2_ = (e2_) - mu22;               \
    ex_ = fmaf(d0_ * d0_, hv20, fmaf(d1_ * d1_, hv21, d2_ * d2_ * hv22));     \
    pc_ = (p2_) * (p2_) * (p2_);                                              \
    mix_ = fmaf(C2 * pc_, __expf(-ex_), mix_);                                \
    d0_ = (e0_) - mu30; d1_ = (e1_) - mu31; d2_ = (e2_) - mu32;               \
    ex_ = fmaf(d0_ * d0_, hv30, fmaf(d1_ * d1_, hv31, d2_ * d2_ * hv32));     \
    pc_ = (p3_) * (p3_) * (p3_);                                              \
    mix_ = fmaf(C3 * pc_, __expf(-ex_), mix_);                                \
    lacc += m_ * __logf(mix_ + 1e-10f);                                       \
} while (0)

// Declare + issue one iteration's 8 vector loads into NAMED registers.
#define LOADSET1(S, v_)                                                       \
    int4   h##S  = H[v_];                                                     \
    float4 f0##S = I0[v_], f1##S = I1[v_], f2##S = I2[v_];                    \
    float4 g0##S = P1[v_], g1##S = P2[v_], g2##S = P3[v_], g3##S = P4[v_];

#define PIXSET1(S)                                                            \
    PIX1(h##S.x, f0##S.x, f1##S.x, f2##S.x, g0##S.x, g1##S.x, g2##S.x, g3##S.x); \
    PIX1(h##S.y, f0##S.y, f1##S.y, f2##S.y, g0##S.y, g1##S.y, g2##S.y, g3##S.y); \
    PIX1(h##S.z, f0##S.z, f1##S.z, f2##S.z, g0##S.z, g1##S.z, g2##S.z, g3##S.z); \
    PIX1(h##S.w, f0##S.w, f1##S.w, f2##S.w, g0##S.w, g1##S.w, g2##S.w, g3##S.w);

#define PIXSET2(S)                                                            \
    PIX2(h##S.x, f0##S.x, f1##S.x, f2##S.x, g0##S.x, g1##S.x, g2##S.x, g3##S.x); \
    PIX2(h##S.y, f0##S.y, f1##S.y, f2##S.y, g0##S.y, g1##S.y, g2##S.y, g3##S.y); \
    PIX2(h##S.z, f0##S.z, f1##S.z, f2##S.z, g0##S.z, g1##S.z, g2##S.z, g3##S.z); \
    PIX2(h##S.w, f0##S.w, f1##S.w, f2##S.w, g0##S.w, g1##S.w, g2##S.w, g3##S.w);

#define DECL_PTRS                                                             \
    const float4* P1 = reinterpret_cast<const float4*>(predictions + (size_t)b * 5 * XY + 1 * XY); \
    const float4* P2 = reinterpret_cast<const float4*>(predictions + (size_t)b * 5 * XY + 2 * XY); \
    const float4* P3 = reinterpret_cast<const float4*>(predictions + (size_t)b * 5 * XY + 3 * XY); \
    const float4* P4 = reinterpret_cast<const float4*>(predictions + (size_t)b * 5 * XY + 4 * XY); \
    const float4* I0 = reinterpret_cast<const float4*>(inputs + (size_t)b * 3 * XY + 0 * XY); \
    const float4* I1 = reinterpret_cast<const float4*>(inputs + (size_t)b * 3 * XY + 1 * XY); \
    const float4* I2 = reinterpret_cast<const float4*>(inputs + (size_t)b * 3 * XY + 2 * XY); \
    const int4*   H  = reinterpret_cast<const int4*>(heart + (size_t)b * XY);

// ---------------------------------------------------------------------------
// Pass 1: weighted moments -> per-block partials. Load-all-then-compute:
// all 16 dwordx4 loads issued before any consumption (sched_barrier pins it);
// __launch_bounds__(256,2) lifts the VGPR cap to 256 so the 64 load-result
// VGPRs + 29 accumulators stay live (round-0's VGPR=44 serialized the loads
// into 2-3-deep dribbles => 1.3 TB/s, latency-bound).
// ---------------------------------------------------------------------------
__global__ __launch_bounds__(256, 2) void pass1_moments(
        const float* __restrict__ predictions,
        const float* __restrict__ inputs,
        const int*   __restrict__ heart,
        char*        __restrict__ wsraw) {
    const int b   = blockIdx.y;
    const int g   = blockIdx.x;
    const int tid = threadIdx.x;
    DECL_PTRS;

    float cnt = 0.f;
    float s0_0 = 0.f, s0_1 = 0.f, s0_2 = 0.f, s0_3 = 0.f;
    float u00 = 0.f, u01 = 0.f, u02 = 0.f, u10 = 0.f, u11 = 0.f, u12 = 0.f;
    float u20 = 0.f, u21 = 0.f, u22 = 0.f, u30 = 0.f, u31 = 0.f, u32 = 0.f;
    float q00 = 0.f, q01 = 0.f, q02 = 0.f, q10 = 0.f, q11 = 0.f, q12 = 0.f;
    float q20 = 0.f, q21 = 0.f, q22 = 0.f, q30 = 0.f, q31 = 0.f, q32 = 0.f;

    const int vA = g * 256 + tid;           // NV/(G*256) == 2 iterations exactly
    const int vB = vA + G * 256;

    LOADSET1(A, vA);                        // 8 loads in flight
    LOADSET1(B, vB);                        // 16 loads in flight
    __builtin_amdgcn_sched_barrier(0);      // don't sink loads below the math
    PIXSET1(A);
    PIXSET1(B);

    __shared__ float sh[4][29];
    const int lane = tid & 63;
    const int wav  = tid >> 6;
    RED(0, cnt);
    RED(1, s0_0); RED(2, s0_1); RED(3, s0_2); RED(4, s0_3);
    RED(5, u00); RED(6, u01); RED(7, u02);
    RED(8, u10); RED(9, u11); RED(10, u12);
    RED(11, u20); RED(12, u21); RED(13, u22);
    RED(14, u30); RED(15, u31); RED(16, u32);
    RED(17, q00); RED(18, q01); RED(19, q02);
    RED(20, q10); RED(21, q11); RED(22, q12);
    RED(23, q20); RED(24, q21); RED(25, q22);
    RED(26, q30); RED(27, q31); RED(28, q32);
    __syncthreads();

    float* p1 = reinterpret_cast<float*>(wsraw + P1OFF);
    if (tid < 29) {
        float v = sh[0][tid] + sh[1][tid] + sh[2][tid] + sh[3][tid];
        p1[(((size_t)b * G + g) << 5) + tid] = v;   // per-block partial
    }
}

// ---------------------------------------------------------------------------
// Batch totals, computed ONCE per batch (round-2 computed them redundantly in
// all 2048 pass2 blocks — that was the 45->97us regression).
// ---------------------------------------------------------------------------
__global__ __launch_bounds__(256) void reduce_totals(char* __restrict__ wsraw) {
    const int b   = blockIdx.x;
    const int tid = threadIdx.x;
    const float* p1 = reinterpret_cast<const float*>(wsraw + P1OFF) + ((size_t)b * G << 5);
    __shared__ double red[8][32];
    const int col = tid & 31, r = tid >> 5;
    double s = 0.0;
    if (col < 29) {
#pragma unroll
        for (int j = r; j < G; j += 8) s += (double)p1[((size_t)j << 5) + col];
    }
    red[r][col] = s;
    __syncthreads();
    if (tid < 29) {
        double t = 0.0;
#pragma unroll
        for (int r2 = 0; r2 < 8; ++r2) t += red[r2][tid];
        reinterpret_cast<double*>(wsraw)[(size_t)b * 32 + tid] = t;
    }
}

// ---------------------------------------------------------------------------
// Pass 2: params (from precomputed totals) -> loglik partial per block.
// Same load-all-then-compute structure; params live in SGPRs via rfl().
// ---------------------------------------------------------------------------
__global__ __launch_bounds__(256, 2) void pass2_loglik(
        const float* __restrict__ predictions,
        const float* __restrict__ inputs,
        const int*   __restrict__ heart,
        char*        __restrict__ wsraw) {
    const int b   = blockIdx.y;
    const int g   = blockIdx.x;
    const int tid = threadIdx.x;
    const double* tot = reinterpret_cast<const double*>(wsraw) + (size_t)b * 32;

    float mu00, mu01, mu02, mu10, mu11, mu12, mu20, mu21, mu22, mu30, mu31, mu32;
    float hv00, hv01, hv02, hv10, hv11, hv12, hv20, hv21, hv22, hv30, hv31, hv32;
    float C0, C1, C2, C3;
    PARAMK(0, mu00, mu01, mu02, hv00, hv01, hv02, C0);
    PARAMK(1, mu10, mu11, mu12, hv10, hv11, hv12, C1);
    PARAMK(2, mu20, mu21, mu22, hv20, hv21, hv22, C2);
    PARAMK(3, mu30, mu31, mu32, hv30, hv31, hv32, C3);
    mu00=rfl(mu00); mu01=rfl(mu01); mu02=rfl(mu02);
    mu10=rfl(mu10); mu11=rfl(mu11); mu12=rfl(mu12);
    mu20=rfl(mu20); mu21=rfl(mu21); mu22=rfl(mu22);
    mu30=rfl(mu30); mu31=rfl(mu31); mu32=rfl(mu32);
    hv00=rfl(hv00); hv01=rfl(hv01); hv02=rfl(hv02);
    hv10=rfl(hv10); hv11=rfl(hv11); hv12=rfl(hv12);
    hv20=rfl(hv20); hv21=rfl(hv21); hv22=rfl(hv22);
    hv30=rfl(hv30); hv31=rfl(hv31); hv32=rfl(hv32);
    C0=rfl(C0); C1=rfl(C1); C2=rfl(C2); C3=rfl(C3);

    DECL_PTRS;

    float lacc = 0.f;
    const int vA = g * 256 + tid;
    const int vB = vA + G * 256;

    LOADSET1(A, vA);
    LOADSET1(B, vB);
    __builtin_amdgcn_sched_barrier(0);
    PIXSET2(A);
    PIXSET2(B);

    __shared__ float sh2[4];
    const int lane = tid & 63;
    const int wav  = tid >> 6;
    {
        float v = waveReduce64(lacc);
        if (lane == 0) sh2[wav] = v;
    }
    __syncthreads();
    if (tid == 0) {
        float* p1 = reinterpret_cast<float*>(wsraw + P1OFF);
        p1[(((size_t)b * G + g) << 5) + 29] = sh2[0] + sh2[1] + sh2[2] + sh2[3];
    }
}

// ---------------------------------------------------------------------------
// Finalize: per-batch loglik sum / mask count, mean over batches.
// ---------------------------------------------------------------------------
__global__ __launch_bounds__(256) void finalize_kernel(
        const char* __restrict__ wsraw, float* __restrict__ out) {
    const float*  p1  = reinterpret_cast<const float*>(wsraw + P1OFF);
    const double* tot = reinterpret_cast<const double*>(wsraw);
    __shared__ double red[16][17];
    const int tid = threadIdx.x;          // 256 threads: 16 batches x 16 lanes
    const int b = tid >> 4, r = tid & 15;
    double s = 0.0;
#pragma unroll
    for (int j = r; j < G; j += 16)
        s += (double)p1[(((size_t)b * G + j) << 5) + 29];
    red[b][r] = s;
    __syncthreads();
    double v = 0.0;
    if (tid < NB) {
        double l = 0.0;
#pragma unroll
        for (int r2 = 0; r2 < 16; ++r2) l += red[tid][r2];
        v = -l / tot[(size_t)tid * 32];   // tot[b][0] = mask count
    }
#pragma unroll
    for (int off = 8; off > 0; off >>= 1) v += __shfl_down(v, off, 64);
    if (tid == 0) out[0] = (float)(v / (double)NB);
}

extern "C" void kernel_launch(void* const* d_in, const int* in_sizes, int n_in,
                              void* d_out, int out_size, void* d_ws, size_t ws_size,
                              hipStream_t stream) {
    const float* predictions = (const float*)d_in[0];
    const float* inputs      = (const float*)d_in[1];
    const int*   heart       = (const int*)d_in[2];
    float* out   = (float*)d_out;
    char*  wsraw = (char*)d_ws;

    pass1_moments<<<dim3(G, NB), 256, 0, stream>>>(predictions, inputs, heart, wsraw);
    reduce_totals<<<dim3(NB),    256, 0, stream>>>(wsraw);
    pass2_loglik <<<dim3(G, NB), 256, 0, stream>>>(predictions, inputs, heart, wsraw);
    finalize_kernel<<<1,         256, 0, stream>>>(wsraw, out);
}

// Round 4
// 195.049 us; speedup vs baseline: 1.3084x; 1.0371x over previous
//
#include <hip/hip_runtime.h>
#include <math.h>

// Problem constants (from reference setup_inputs)
constexpr int NB = 16;          // batches
constexpr int XY = 512 * 512;   // pixels per image
constexpr int NV = XY / 4;      // float4 vectors per image

constexpr int G1 = 128;         // pass1 blocks/batch; lane-indexed: NIT1 = NV/(G1*64) = 8
constexpr int NIT1 = NV / (G1 * 64);
constexpr int G2 = 64;          // pass2 blocks/batch; tid-indexed: NIT2 = NV/(G2*256) = 4
constexpr int NIT2 = NV / (G2 * 256);

// Workspace layout (every location written before read => no memset, no atomics,
// poison-safe):
//   bytes [0 .. 4095]      : double tot[NB][32]        (29 used; reduce_totals)
//   bytes [4096 .. +256K]  : float  p1[NB][G1][32]     (29 used; pass1 moments)
//   bytes [266240 .. +4K]  : float  p2[NB][G2]         (pass2 loglik partials)
constexpr int P1OFF = 4096;
constexpr int P2OFF = P1OFF + NB * G1 * 32 * 4;   // 266240

__device__ __forceinline__ float waveReduce64(float v) {
#pragma unroll
    for (int off = 32; off > 0; off >>= 1) v += __shfl_down(v, off, 64);
    return v;
}

// Coerce a block-uniform float into an SGPR (frees VGPRs in the pass2 loop).
__device__ __forceinline__ float rfl(float x) {
    return __uint_as_float(__builtin_amdgcn_readfirstlane(__float_as_uint(x)));
}

// Wave-specialized per-pixel moment accumulation: ONE component per wave,
// 8 live accumulators instead of 29 (round-3 post-mortem: 29 acc + 8 ptrs
// left zero VGPR room to pipeline loads; pass1 pinned at 235 cyc/load).
#define PIXW(h_, p_, e0_, e1_, e2_) do {                                      \
    float mm_ = ((h_) == 1) ? 1.f : 0.f;                                      \
    cnt += mm_;                                                               \
    float w_ = (p_) * mm_;                                                    \
    s0 += w_;                                                                 \
    float t_;                                                                 \
    t_ = w_ * (e0_); u0 += t_; q0 = fmaf(t_, (e0_), q0);                      \
    t_ = w_ * (e1_); u1 += t_; q1 = fmaf(t_, (e1_), q1);                      \
    t_ = w_ * (e2_); u2 += t_; q2 = fmaf(t_, (e2_), q2);                      \
} while (0)

// Per-component parameter reconstruction (block-uniform, f64 for the
// cancellation in S2 - 2 mu S1 + mu^2 S0). Reads the precomputed `tot` doubles.
#define PARAMK(K_, mu0_, mu1_, mu2_, h0_, h1_, h2_, C_) {                     \
    double S0_ = tot[1 + (K_)];                                               \
    double den_ = S0_ + 1e-10;                                                \
    double Cd_ = 1.0;                                                         \
    double S1_, S2_, muv_, var_;                                              \
    S1_ = tot[5 + (K_)*3 + 0]; S2_ = tot[17 + (K_)*3 + 0];                    \
    muv_ = S1_ / den_;                                                        \
    var_ = (S2_ - 2.0 * muv_ * S1_ + muv_ * muv_ * S0_) / den_ + 1e-10;       \
    mu0_ = (float)muv_; h0_ = (float)(0.5 / var_);                            \
    Cd_ *= 1.0 / sqrt(6.283185307179586 * var_);                              \
    S1_ = tot[5 + (K_)*3 + 1]; S2_ = tot[17 + (K_)*3 + 1];                    \
    muv_ = S1_ / den_;                                                        \
    var_ = (S2_ - 2.0 * muv_ * S1_ + muv_ * muv_ * S0_) / den_ + 1e-10;       \
    mu1_ = (float)muv_; h1_ = (float)(0.5 / var_);                            \
    Cd_ *= 1.0 / sqrt(6.283185307179586 * var_);                              \
    S1_ = tot[5 + (K_)*3 + 2]; S2_ = tot[17 + (K_)*3 + 2];                    \
    muv_ = S1_ / den_;                                                        \
    var_ = (S2_ - 2.0 * muv_ * S1_ + muv_ * muv_ * S0_) / den_ + 1e-10;       \
    mu2_ = (float)muv_; h2_ = (float)(0.5 / var_);                            \
    Cd_ *= 1.0 / sqrt(6.283185307179586 * var_);                              \
    C_ = (float)Cd_;                                                          \
}

#define PIX2(h_, e0_, e1_, e2_, p0_, p1_, p2_, p3_) do {                      \
    float m_ = ((h_) == 1) ? 1.f : 0.f;                                       \
    float d0_, d1_, d2_, ex_, pc_;                                            \
    float mix_;                                                               \
    d0_ = (e0_) - mu00; d1_ = (e1_) - mu01; d2_ = (e2_) - mu02;               \
    ex_ = fmaf(d0_ * d0_, hv00, fmaf(d1_ * d1_, hv01, d2_ * d2_ * hv02));     \
    pc_ = (p0_) * (p0_) * (p0_);                                              \
    mix_ = C0 * pc_ * __expf(-ex_);                                           \
    d0_ = (e0_) - mu10; d1_ = (e1_) - mu11; d2_ = (e2_) - mu12;               \
    ex_ = fmaf(d0_ * d0_, hv10, fmaf(d1_ * d1_, hv11, d2_ * d2_ * hv12));     \
    pc_ = (p1_) * (p1_) * (p1_);                                              \
    mix_ = fmaf(C1 * pc_, __expf(-ex_), mix_);                                \
    d0_ = (e0_) - mu20; d1_ = (e1_) - mu21; d2_ = (e2_) - mu22;               \
    ex_ = fmaf(d0_ * d0_, hv20, fmaf(d1_ * d1_, hv21, d2_ * d2_ * hv22));     \
    pc_ = (p2_) * (p2_) * (p2_);                                              \
    mix_ = fmaf(C2 * pc_, __expf(-ex_), mix_);                                \
    d0_ = (e0_) - mu30; d1_ = (e1_) - mu31; d2_ = (e2_) - mu32;               \
    ex_ = fmaf(d0_ * d0_, hv30, fmaf(d1_ * d1_, hv31, d2_ * d2_ * hv32));     \
    pc_ = (p3_) * (p3_) * (p3_);                                              \
    mix_ = fmaf(C3 * pc_, __expf(-ex_), mix_);                                \
    lacc += m_ * __logf(mix_ + 1e-10f);                                       \
} while (0)

// ---------------------------------------------------------------------------
// Pass 1 (wave-specialized): wave k of each block accumulates component k's
// 7 moments (+cnt) over the block's pixel window. 5 streams/wave, 8 live
// accumulators, no LDS, no __syncthreads. Redundant heart/input loads across
// the 4 waves coalesce in L1/L2 MSHRs (same lines within a short window).
// ---------------------------------------------------------------------------
__global__ __launch_bounds__(256) void pass1_moments(
        const float* __restrict__ predictions,
        const float* __restrict__ inputs,
        const int*   __restrict__ heart,
        char*        __restrict__ wsraw) {
    const int b    = blockIdx.y;
    const int g    = blockIdx.x;
    const int tid  = threadIdx.x;
    const int lane = tid & 63;
    const int wav  = tid >> 6;        // component index k = wav

    const float4* PK = reinterpret_cast<const float4*>(
        predictions + (size_t)b * 5 * XY + (size_t)(1 + wav) * XY);
    const float4* I0 = reinterpret_cast<const float4*>(inputs + (size_t)b * 3 * XY + 0 * XY);
    const float4* I1 = reinterpret_cast<const float4*>(inputs + (size_t)b * 3 * XY + 1 * XY);
    const float4* I2 = reinterpret_cast<const float4*>(inputs + (size_t)b * 3 * XY + 2 * XY);
    const int4*   H  = reinterpret_cast<const int4*>(heart + (size_t)b * XY);

    float cnt = 0.f, s0 = 0.f;
    float u0 = 0.f, u1 = 0.f, u2 = 0.f;
    float q0 = 0.f, q1 = 0.f, q2 = 0.f;

#pragma unroll 4
    for (int it = 0; it < NIT1; ++it) {
        const int v = g * 64 + lane + it * (G1 * 64);
        int4   h  = H[v];
        float4 pk = PK[v];
        float4 f0 = I0[v], f1 = I1[v], f2 = I2[v];
        PIXW(h.x, pk.x, f0.x, f1.x, f2.x);
        PIXW(h.y, pk.y, f0.y, f1.y, f2.y);
        PIXW(h.z, pk.z, f0.z, f1.z, f2.z);
        PIXW(h.w, pk.w, f0.w, f1.w, f2.w);
    }

    s0 = waveReduce64(s0);
    u0 = waveReduce64(u0); u1 = waveReduce64(u1); u2 = waveReduce64(u2);
    q0 = waveReduce64(q0); q1 = waveReduce64(q1); q2 = waveReduce64(q2);
    if (wav == 0) cnt = waveReduce64(cnt);

    if (lane == 0) {
        float* dst = reinterpret_cast<float*>(wsraw + P1OFF) + (((size_t)b * G1 + g) << 5);
        dst[1 + wav]           = s0;
        dst[5 + 3 * wav + 0]   = u0;
        dst[5 + 3 * wav + 1]   = u1;
        dst[5 + 3 * wav + 2]   = u2;
        dst[17 + 3 * wav + 0]  = q0;
        dst[17 + 3 * wav + 1]  = q1;
        dst[17 + 3 * wav + 2]  = q2;
        if (wav == 0) dst[0]   = cnt;
    }
}

// ---------------------------------------------------------------------------
// Batch totals, computed ONCE per batch (f64).
// ---------------------------------------------------------------------------
__global__ __launch_bounds__(256) void reduce_totals(char* __restrict__ wsraw) {
    const int b   = blockIdx.x;
    const int tid = threadIdx.x;
    const float* p1 = reinterpret_cast<const float*>(wsraw + P1OFF) + ((size_t)b * G1 << 5);
    __shared__ double red[8][32];
    const int col = tid & 31, r = tid >> 5;
    double s = 0.0;
    if (col < 29) {
#pragma unroll
        for (int j = r; j < G1; j += 8) s += (double)p1[((size_t)j << 5) + col];
    }
    red[r][col] = s;
    __syncthreads();
    if (tid < 29) {
        double t = 0.0;
#pragma unroll
        for (int r2 = 0; r2 < 8; ++r2) t += red[r2][tid];
        reinterpret_cast<double*>(wsraw)[(size_t)b * 32 + tid] = t;
    }
}

// ---------------------------------------------------------------------------
// Pass 2: params (from precomputed totals, in SGPRs) -> loglik partials.
// 4-iteration grid-stride, unroll 2, so consecutive 8-load batches overlap.
// ---------------------------------------------------------------------------
__global__ __launch_bounds__(256) void pass2_loglik(
        const float* __restrict__ predictions,
        const float* __restrict__ inputs,
        const int*   __restrict__ heart,
        char*        __restrict__ wsraw) {
    const int b   = blockIdx.y;
    const int g   = blockIdx.x;
    const int tid = threadIdx.x;
    const double* tot = reinterpret_cast<const double*>(wsraw) + (size_t)b * 32;

    float mu00, mu01, mu02, mu10, mu11, mu12, mu20, mu21, mu22, mu30, mu31, mu32;
    float hv00, hv01, hv02, hv10, hv11, hv12, hv20, hv21, hv22, hv30, hv31, hv32;
    float C0, C1, C2, C3;
    PARAMK(0, mu00, mu01, mu02, hv00, hv01, hv02, C0);
    PARAMK(1, mu10, mu11, mu12, hv10, hv11, hv12, C1);
    PARAMK(2, mu20, mu21, mu22, hv20, hv21, hv22, C2);
    PARAMK(3, mu30, mu31, mu32, hv30, hv31, hv32, C3);
    mu00=rfl(mu00); mu01=rfl(mu01); mu02=rfl(mu02);
    mu10=rfl(mu10); mu11=rfl(mu11); mu12=rfl(mu12);
    mu20=rfl(mu20); mu21=rfl(mu21); mu22=rfl(mu22);
    mu30=rfl(mu30); mu31=rfl(mu31); mu32=rfl(mu32);
    hv00=rfl(hv00); hv01=rfl(hv01); hv02=rfl(hv02);
    hv10=rfl(hv10); hv11=rfl(hv11); hv12=rfl(hv12);
    hv20=rfl(hv20); hv21=rfl(hv21); hv22=rfl(hv22);
    hv30=rfl(hv30); hv31=rfl(hv31); hv32=rfl(hv32);
    C0=rfl(C0); C1=rfl(C1); C2=rfl(C2); C3=rfl(C3);

    const float4* P1 = reinterpret_cast<const float4*>(predictions + (size_t)b * 5 * XY + 1 * XY);
    const float4* P2 = reinterpret_cast<const float4*>(predictions + (size_t)b * 5 * XY + 2 * XY);
    const float4* P3 = reinterpret_cast<const float4*>(predictions + (size_t)b * 5 * XY + 3 * XY);
    const float4* P4 = reinterpret_cast<const float4*>(predictions + (size_t)b * 5 * XY + 4 * XY);
    const float4* I0 = reinterpret_cast<const float4*>(inputs + (size_t)b * 3 * XY + 0 * XY);
    const float4* I1 = reinterpret_cast<const float4*>(inputs + (size_t)b * 3 * XY + 1 * XY);
    const float4* I2 = reinterpret_cast<const float4*>(inputs + (size_t)b * 3 * XY + 2 * XY);
    const int4*   H  = reinterpret_cast<const int4*>(heart + (size_t)b * XY);

    float lacc = 0.f;
#pragma unroll 2
    for (int it = 0; it < NIT2; ++it) {
        const int v = g * 256 + tid + it * (G2 * 256);
        int4   h  = H[v];
        float4 f0 = I0[v], f1 = I1[v], f2 = I2[v];
        float4 g0 = P1[v], g1 = P2[v], g2 = P3[v], g3 = P4[v];
        PIX2(h.x, f0.x, f1.x, f2.x, g0.x, g1.x, g2.x, g3.x);
        PIX2(h.y, f0.y, f1.y, f2.y, g0.y, g1.y, g2.y, g3.y);
        PIX2(h.z, f0.z, f1.z, f2.z, g0.z, g1.z, g2.z, g3.z);
        PIX2(h.w, f0.w, f1.w, f2.w, g0.w, g1.w, g2.w, g3.w);
    }

    __shared__ float sh2[4];
    const int lane = tid & 63;
    const int wav  = tid >> 6;
    {
        float v = waveReduce64(lacc);
        if (lane == 0) sh2[wav] = v;
    }
    __syncthreads();
    if (tid == 0) {
        float* p2 = reinterpret_cast<float*>(wsraw + P2OFF);
        p2[(size_t)b * G2 + g] = sh2[0] + sh2[1] + sh2[2] + sh2[3];
    }
}

// ---------------------------------------------------------------------------
// Finalize: per-batch loglik sum / mask count, mean over batches.
// ---------------------------------------------------------------------------
__global__ __launch_bounds__(256) void finalize_kernel(
        const char* __restrict__ wsraw, float* __restrict__ out) {
    const float*  p2  = reinterpret_cast<const float*>(wsraw + P2OFF);
    const double* tot = reinterpret_cast<const double*>(wsraw);
    __shared__ double red[16][17];
    const int tid = threadIdx.x;          // 256 threads: 16 batches x 16 lanes
    const int b = tid >> 4, r = tid & 15;
    double s = 0.0;
#pragma unroll
    for (int j = r; j < G2; j += 16)
        s += (double)p2[(size_t)b * G2 + j];
    red[b][r] = s;
    __syncthreads();
    double v = 0.0;
    if (tid < NB) {
        double l = 0.0;
#pragma unroll
        for (int r2 = 0; r2 < 16; ++r2) l += red[tid][r2];
        v = -l / tot[(size_t)tid * 32];   // tot[b][0] = mask count
    }
#pragma unroll
    for (int off = 8; off > 0; off >>= 1) v += __shfl_down(v, off, 64);
    if (tid == 0) out[0] = (float)(v / (double)NB);
}

extern "C" void kernel_launch(void* const* d_in, const int* in_sizes, int n_in,
                              void* d_out, int out_size, void* d_ws, size_t ws_size,
                              hipStream_t stream) {
    const float* predictions = (const float*)d_in[0];
    const float* inputs      = (const float*)d_in[1];
    const int*   heart       = (const int*)d_in[2];
    float* out   = (float*)d_out;
    char*  wsraw = (char*)d_ws;

    pass1_moments<<<dim3(G1, NB), 256, 0, stream>>>(predictions, inputs, heart, wsraw);
    reduce_totals<<<dim3(NB),     256, 0, stream>>>(wsraw);
    pass2_loglik <<<dim3(G2, NB), 256, 0, stream>>>(predictions, inputs, heart, wsraw);
    finalize_kernel<<<1,          256, 0, stream>>>(wsraw, out);
}

// Round 5
// 194.787 us; speedup vs baseline: 1.3101x; 1.0013x over previous
//
#include <hip/hip_runtime.h>
#include <math.h>
#include <stdint.h>

// Problem constants (from reference setup_inputs)
constexpr int NB  = 16;          // batches
constexpr int XY  = 512 * 512;   // pixels per image
constexpr int NV  = XY / 4;      // float4 vectors per plane per batch (65536)

constexpr int G1  = 32;          // blocks per batch (both passes) -> 512 blocks total
constexpr int WIN = 256;         // float4 vecs per window (4 KB per plane)
constexpr int NIT = NV / (G1 * WIN);   // 8 windows per block (compile-time)
constexpr int NPL = 8;           // staged planes: H, I0,I1,I2, P1,P2,P3,P4
static_assert((NIT & 1) == 0, "LDS-reuse epilogue assumes last window lives in buf1");

// Workspace layout (every location written before read => no memset, no atomics,
// poison-safe):
//   bytes [0 .. 4095]    : double tot[NB][32]      (29 used; reduce_totals)
//   bytes [P1OFF ..]     : float  p1[NB][G1][32]   (29 used; pass1 moments)
//   bytes [P2OFF ..]     : float  p2[NB][G1]       (pass2 loglik partials)
constexpr int P1OFF = 4096;
constexpr int P2OFF = P1OFF + NB * G1 * 32 * 4;   // 69632

__device__ __forceinline__ float waveReduce64(float v) {
#pragma unroll
    for (int off = 32; off > 0; off >>= 1) v += __shfl_down(v, off, 64);
    return v;
}

// Coerce a block-uniform float into an SGPR (frees VGPRs in the pass2 loop).
__device__ __forceinline__ float rfl(float x) {
    return __uint_as_float(__builtin_amdgcn_readfirstlane(__float_as_uint(x)));
}

// Async global->LDS DMA, 16 B per lane. LDS dest is wave-uniform base + lane*16
// (HW rule, m104); global src is per-lane. Zero VGPRs consumed for data.
__device__ __forceinline__ void gl2lds(const void* g, void* l) {
    __builtin_amdgcn_global_load_lds(
        (__attribute__((address_space(1))) void*)(void*)g,
        (__attribute__((address_space(3))) void*)l,
        16, 0, 0);
}

// Straight-line per-pixel moment accumulation (29 named scalar accumulators).
#define PIX1(h_, e0_, e1_, e2_, p0_, p1_, p2_, p3_) do {                      \
    float mm_ = ((h_) == 1) ? 1.f : 0.f;                                      \
    cnt += mm_;                                                               \
    float w0_ = (p0_) * mm_, w1_ = (p1_) * mm_, w2_ = (p2_) * mm_,            \
          w3_ = (p3_) * mm_;                                                  \
    s0_0 += w0_; s0_1 += w1_; s0_2 += w2_; s0_3 += w3_;                       \
    float t_;                                                                 \
    t_ = w0_ * (e0_); u00 += t_; q00 = fmaf(t_, (e0_), q00);                  \
    t_ = w0_ * (e1_); u01 += t_; q01 = fmaf(t_, (e1_), q01);                  \
    t_ = w0_ * (e2_); u02 += t_; q02 = fmaf(t_, (e2_), q02);                  \
    t_ = w1_ * (e0_); u10 += t_; q10 = fmaf(t_, (e0_), q10);                  \
    t_ = w1_ * (e1_); u11 += t_; q11 = fmaf(t_, (e1_), q11);                  \
    t_ = w1_ * (e2_); u12 += t_; q12 = fmaf(t_, (e2_), q12);                  \
    t_ = w2_ * (e0_); u20 += t_; q20 = fmaf(t_, (e0_), q20);                  \
    t_ = w2_ * (e1_); u21 += t_; q21 = fmaf(t_, (e1_), q21);                  \
    t_ = w2_ * (e2_); u22 += t_; q22 = fmaf(t_, (e2_), q22);                  \
    t_ = w3_ * (e0_); u30 += t_; q30 = fmaf(t_, (e0_), q30);                  \
    t_ = w3_ * (e1_); u31 += t_; q31 = fmaf(t_, (e1_), q31);                  \
    t_ = w3_ * (e2_); u32 += t_; q32 = fmaf(t_, (e2_), q32);                  \
} while (0)

// Per-component parameter reconstruction (block-uniform, f64 for the
// cancellation in S2 - 2 mu S1 + mu^2 S0). Reads the precomputed `tot` doubles.
#define PARAMK(K_, mu0_, mu1_, mu2_, h0_, h1_, h2_, C_) {                     \
    double S0_ = tot[1 + (K_)];                                               \
    double den_ = S0_ + 1e-10;                                                \
    double Cd_ = 1.0;                                                         \
    double S1_, S2_, muv_, var_;                                              \
    S1_ = tot[5 + (K_)*3 + 0]; S2_ = tot[17 + (K_)*3 + 0];                    \
    muv_ = S1_ / den_;                                                        \
    var_ = (S2_ - 2.0 * muv_ * S1_ + muv_ * muv_ * S0_) / den_ + 1e-10;       \
    mu0_ = (float)muv_; h0_ = (float)(0.5 / var_);                            \
    Cd_ *= 1.0 / sqrt(6.283185307179586 * var_);                              \
    S1_ = tot[5 + (K_)*3 + 1]; S2_ = tot[17 + (K_)*3 + 1];                    \
    muv_ = S1_ / den_;                                                        \
    var_ = (S2_ - 2.0 * muv_ * S1_ + muv_ * muv_ * S0_) / den_ + 1e-10;       \
    mu1_ = (float)muv_; h1_ = (float)(0.5 / var_);                            \
    Cd_ *= 1.0 / sqrt(6.283185307179586 * var_);                              \
    S1_ = tot[5 + (K_)*3 + 2]; S2_ = tot[17 + (K_)*3 + 2];                    \
    muv_ = S1_ / den_;                                                        \
    var_ = (S2_ - 2.0 * muv_ * S1_ + muv_ * muv_ * S0_) / den_ + 1e-10;       \
    mu2_ = (float)muv_; h2_ = (float)(0.5 / var_);                            \
    Cd_ *= 1.0 / sqrt(6.283185307179586 * var_);                              \
    C_ = (float)Cd_;                                                          \
}

#define PIX2(h_, e0_, e1_, e2_, p0_, p1_, p2_, p3_) do {                      \
    float m_ = ((h_) == 1) ? 1.f : 0.f;                                       \
    float d0_, d1_, d2_, ex_, pc_;                                            \
    float mix_;                                                               \
    d0_ = (e0_) - mu00; d1_ = (e1_) - mu01; d2_ = (e2_) - mu02;               \
    ex_ = fmaf(d0_ * d0_, hv00, fmaf(d1_ * d1_, hv01, d2_ * d2_ * hv02));     \
    pc_ = (p0_) * (p0_) * (p0_);                                              \
    mix_ = C0 * pc_ * __expf(-ex_);                                           \
    d0_ = (e0_) - mu10; d1_ = (e1_) - mu11; d2_ = (e2_) - mu12;               \
    ex_ = fmaf(d0_ * d0_, hv10, fmaf(d1_ * d1_, hv11, d2_ * d2_ * hv12));     \
    pc_ = (p1_) * (p1_) * (p1_);                                              \
    mix_ = fmaf(C1 * pc_, __expf(-ex_), mix_);                                \
    d0_ = (e0_) - mu20; d1_ = (e1_) - mu21; d2_ = (e2_) - mu22;               \
    ex_ = fmaf(d0_ * d0_, hv20, fmaf(d1_ * d1_, hv21, d2_ * d2_ * hv22));     \
    pc_ = (p2_) * (p2_) * (p2_);                                              \
    mix_ = fmaf(C2 * pc_, __expf(-ex_), mix_);                                \
    d0_ = (e0_) - mu30; d1_ = (e1_) - mu31; d2_ = (e2_) - mu32;               \
    ex_ = fmaf(d0_ * d0_, hv30, fmaf(d1_ * d1_, hv31, d2_ * d2_ * hv32));     \
    pc_ = (p3_) * (p3_) * (p3_);                                              \
    mix_ = fmaf(C3 * pc_, __expf(-ex_), mix_);                                \
    lacc += m_ * __logf(mix_ + 1e-10f);                                       \
} while (0)

// Issue the 8 async DMA loads for window IT_ into LDS buffer B_ (0/1).
// Each wave stages its own 1KB chunk per plane: lds dest = buf + plane*4096 +
// wav*1024 (+ lane*16 by HW); global src per-lane.
#define STAGE(B_, IT_) do {                                                   \
    const size_t o_ = (size_t)(IT_) * 4096;                                   \
    char* lb_ = lds + (B_) * (NPL * 4096) + wav * 1024;                       \
    gl2lds(gH  + o_, lb_ + 0 * 4096);                                         \
    gl2lds(gI0 + o_, lb_ + 1 * 4096);                                         \
    gl2lds(gI1 + o_, lb_ + 2 * 4096);                                         \
    gl2lds(gI2 + o_, lb_ + 3 * 4096);                                         \
    gl2lds(gP1 + o_, lb_ + 4 * 4096);                                         \
    gl2lds(gP2 + o_, lb_ + 5 * 4096);                                         \
    gl2lds(gP3 + o_, lb_ + 6 * 4096);                                         \
    gl2lds(gP4 + o_, lb_ + 7 * 4096);                                         \
} while (0)

// Load this thread's 8 staged vectors from LDS buffer B_ into named regs.
#define LOADREGS(B_)                                                          \
    const char* cb_ = lds + (B_) * (NPL * 4096);                              \
    int4   h  = *(const int4*)  (cb_ + 0 * 4096 + tid * 16);                  \
    float4 f0 = *(const float4*)(cb_ + 1 * 4096 + tid * 16);                  \
    float4 f1 = *(const float4*)(cb_ + 2 * 4096 + tid * 16);                  \
    float4 f2 = *(const float4*)(cb_ + 3 * 4096 + tid * 16);                  \
    float4 g0 = *(const float4*)(cb_ + 4 * 4096 + tid * 16);                  \
    float4 g1 = *(const float4*)(cb_ + 5 * 4096 + tid * 16);                  \
    float4 g2 = *(const float4*)(cb_ + 6 * 4096 + tid * 16);                  \
    float4 g3 = *(const float4*)(cb_ + 7 * 4096 + tid * 16);

#define DECL_GSRC                                                             \
    const char* Pb = (const char*)(predictions + (size_t)b * 5 * XY);         \
    const char* Ib = (const char*)(inputs      + (size_t)b * 3 * XY);         \
    const char* Hb = (const char*)(heart       + (size_t)b * XY);             \
    const size_t vb = (size_t)(g * (NIT * WIN) + wav * 64 + lane) * 16;       \
    const char* gH  = Hb + vb;                                                \
    const char* gI0 = Ib + 0 * (size_t)XY * 4 + vb;                           \
    const char* gI1 = Ib + 1 * (size_t)XY * 4 + vb;                           \
    const char* gI2 = Ib + 2 * (size_t)XY * 4 + vb;                           \
    const char* gP1 = Pb + 1 * (size_t)XY * 4 + vb;                           \
    const char* gP2 = Pb + 2 * (size_t)XY * 4 + vb;                           \
    const char* gP3 = Pb + 3 * (size_t)XY * 4 + vb;                           \
    const char* gP4 = Pb + 4 * (size_t)XY * 4 + vb;

#define WAIT_LGKM  asm volatile("s_waitcnt lgkmcnt(0)" ::: "memory")
#define WAIT_VM    asm volatile("s_waitcnt vmcnt(0)"   ::: "memory")

// ---------------------------------------------------------------------------
// Pass 1: DMA-staged (global_load_lds, zero-VGPR streaming) weighted moments.
// Unique traffic only (r4's wave-specialization wasted its 10.9 B/cyc/CU on
// 2.5x redundancy); compute runs from LDS with the full 29 accumulators.
// Main loop is barrier-free: each wave reads only its own staged chunks, so
// per-wave vmcnt/lgkmcnt ordering suffices (one barrier before the reduction).
// ---------------------------------------------------------------------------
__global__ __launch_bounds__(256) void pass1_moments(
        const float* __restrict__ predictions,
        const float* __restrict__ inputs,
        const int*   __restrict__ heart,
        char*        __restrict__ wsraw) {
    const int b    = blockIdx.y;
    const int g    = blockIdx.x;
    const int tid  = threadIdx.x;
    const int lane = tid & 63;
    const int wav  = tid >> 6;

    __shared__ __align__(16) char lds[2 * NPL * 4096];   // 64 KB, double-buffered

    DECL_GSRC;

    float cnt = 0.f;
    float s0_0 = 0.f, s0_1 = 0.f, s0_2 = 0.f, s0_3 = 0.f;
    float u00 = 0.f, u01 = 0.f, u02 = 0.f, u10 = 0.f, u11 = 0.f, u12 = 0.f;
    float u20 = 0.f, u21 = 0.f, u22 = 0.f, u30 = 0.f, u31 = 0.f, u32 = 0.f;
    float q00 = 0.f, q01 = 0.f, q02 = 0.f, q10 = 0.f, q11 = 0.f, q12 = 0.f;
    float q20 = 0.f, q21 = 0.f, q22 = 0.f, q30 = 0.f, q31 = 0.f, q32 = 0.f;

    STAGE(0, 0);
    WAIT_VM;
    for (int it = 0; it < NIT; ++it) {
        LOADREGS(it & 1);
        WAIT_LGKM;                       // ds_reads done before next STAGE may
                                         // overwrite this buffer (WAR, per-wave)
        if (it + 1 < NIT) STAGE((it + 1) & 1, it + 1);
        PIX1(h.x, f0.x, f1.x, f2.x, g0.x, g1.x, g2.x, g3.x);
        PIX1(h.y, f0.y, f1.y, f2.y, g0.y, g1.y, g2.y, g3.y);
        PIX1(h.z, f0.z, f1.z, f2.z, g0.z, g1.z, g2.z, g3.z);
        PIX1(h.w, f0.w, f1.w, f2.w, g0.w, g1.w, g2.w, g3.w);
        WAIT_VM;                         // next window's DMA complete
    }

    __syncthreads();                     // all waves done computing -> reuse LDS
    float* shred = reinterpret_cast<float*>(lds);
#define REDS(i_, var_) { float r_ = waveReduce64(var_); if (lane == 0) shred[wav * 32 + (i_)] = r_; }
    REDS(0, cnt);
    REDS(1, s0_0); REDS(2, s0_1); REDS(3, s0_2); REDS(4, s0_3);
    REDS(5, u00); REDS(6, u01); REDS(7, u02);
    REDS(8, u10); REDS(9, u11); REDS(10, u12);
    REDS(11, u20); REDS(12, u21); REDS(13, u22);
    REDS(14, u30); REDS(15, u31); REDS(16, u32);
    REDS(17, q00); REDS(18, q01); REDS(19, q02);
    REDS(20, q10); REDS(21, q11); REDS(22, q12);
    REDS(23, q20); REDS(24, q21); REDS(25, q22);
    REDS(26, q30); REDS(27, q31); REDS(28, q32);
#undef REDS
    __syncthreads();
    if (tid < 29) {
        float v = shred[tid] + shred[32 + tid] + shred[64 + tid] + shred[96 + tid];
        float* p1 = reinterpret_cast<float*>(wsraw + P1OFF);
        p1[(((size_t)b * G1 + g) << 5) + tid] = v;
    }
}

// ---------------------------------------------------------------------------
// Batch totals, computed ONCE per batch (f64).
// ---------------------------------------------------------------------------
__global__ __launch_bounds__(256) void reduce_totals(char* __restrict__ wsraw) {
    const int b   = blockIdx.x;
    const int tid = threadIdx.x;
    const float* p1 = reinterpret_cast<const float*>(wsraw + P1OFF) + ((size_t)b * G1 << 5);
    __shared__ double red[8][32];
    const int col = tid & 31, r = tid >> 5;
    double s = 0.0;
    if (col < 29) {
#pragma unroll
        for (int j = r; j < G1; j += 8) s += (double)p1[((size_t)j << 5) + col];
    }
    red[r][col] = s;
    __syncthreads();
    if (tid < 29) {
        double t = 0.0;
#pragma unroll
        for (int r2 = 0; r2 < 8; ++r2) t += red[r2][tid];
        reinterpret_cast<double*>(wsraw)[(size_t)b * 32 + tid] = t;
    }
}

// ---------------------------------------------------------------------------
// Pass 2: params (from precomputed totals, in SGPRs) -> loglik partials.
// Same DMA-staged pipeline; compute state is 1 accumulator + SGPR params.
// ---------------------------------------------------------------------------
__global__ __launch_bounds__(256) void pass2_loglik(
        const float* __restrict__ predictions,
        const float* __restrict__ inputs,
        const int*   __restrict__ heart,
        char*        __restrict__ wsraw) {
    const int b    = blockIdx.y;
    const int g    = blockIdx.x;
    const int tid  = threadIdx.x;
    const int lane = tid & 63;
    const int wav  = tid >> 6;

    __shared__ __align__(16) char lds[2 * NPL * 4096];   // 64 KB, double-buffered

    const double* tot = reinterpret_cast<const double*>(wsraw) + (size_t)b * 32;

    float mu00, mu01, mu02, mu10, mu11, mu12, mu20, mu21, mu22, mu30, mu31, mu32;
    float hv00, hv01, hv02, hv10, hv11, hv12, hv20, hv21, hv22, hv30, hv31, hv32;
    float C0, C1, C2, C3;
    PARAMK(0, mu00, mu01, mu02, hv00, hv01, hv02, C0);
    PARAMK(1, mu10, mu11, mu12, hv10, hv11, hv12, C1);
    PARAMK(2, mu20, mu21, mu22, hv20, hv21, hv22, C2);
    PARAMK(3, mu30, mu31, mu32, hv30, hv31, hv32, C3);
    mu00=rfl(mu00); mu01=rfl(mu01); mu02=rfl(mu02);
    mu10=rfl(mu10); mu11=rfl(mu11); mu12=rfl(mu12);
    mu20=rfl(mu20); mu21=rfl(mu21); mu22=rfl(mu22);
    mu30=rfl(mu30); mu31=rfl(mu31); mu32=rfl(mu32);
    hv00=rfl(hv00); hv01=rfl(hv01); hv02=rfl(hv02);
    hv10=rfl(hv10); hv11=rfl(hv11); hv12=rfl(hv12);
    hv20=rfl(hv20); hv21=rfl(hv21); hv22=rfl(hv22);
    hv30=rfl(hv30); hv31=rfl(hv31); hv32=rfl(hv32);
    C0=rfl(C0); C1=rfl(C1); C2=rfl(C2); C3=rfl(C3);

    DECL_GSRC;

    float lacc = 0.f;

    STAGE(0, 0);
    WAIT_VM;
    for (int it = 0; it < NIT; ++it) {
        LOADREGS(it & 1);
        WAIT_LGKM;
        if (it + 1 < NIT) STAGE((it + 1) & 1, it + 1);
        PIX2(h.x, f0.x, f1.x, f2.x, g0.x, g1.x, g2.x, g3.x);
        PIX2(h.y, f0.y, f1.y, f2.y, g0.y, g1.y, g2.y, g3.y);
        PIX2(h.z, f0.z, f1.z, f2.z, g0.z, g1.z, g2.z, g3.z);
        PIX2(h.w, f0.w, f1.w, f2.w, g0.w, g1.w, g2.w, g3.w);
        WAIT_VM;
    }

    __syncthreads();
    float* shred = reinterpret_cast<float*>(lds);
    {
        float v = waveReduce64(lacc);
        if (lane == 0) shred[wav] = v;
    }
    __syncthreads();
    if (tid == 0) {
        float* p2 = reinterpret_cast<float*>(wsraw + P2OFF);
        p2[(size_t)b * G1 + g] = shred[0] + shred[1] + shred[2] + shred[3];
    }
}

// ---------------------------------------------------------------------------
// Finalize: per-batch loglik sum / mask count, mean over batches.
// ---------------------------------------------------------------------------
__global__ __launch_bounds__(256) void finalize_kernel(
        const char* __restrict__ wsraw, float* __restrict__ out) {
    const float*  p2  = reinterpret_cast<const float*>(wsraw + P2OFF);
    const double* tot = reinterpret_cast<const double*>(wsraw);
    __shared__ double red[16][17];
    const int tid = threadIdx.x;          // 256 threads: 16 batches x 16 lanes
    const int b = tid >> 4, r = tid & 15;
    double s = 0.0;
#pragma unroll
    for (int j = r; j < G1; j += 16)
        s += (double)p2[(size_t)b * G1 + j];
    red[b][r] = s;
    __syncthreads();
    double v = 0.0;
    if (tid < NB) {
        double l = 0.0;
#pragma unroll
        for (int r2 = 0; r2 < 16; ++r2) l += red[tid][r2];
        v = -l / tot[(size_t)tid * 32];   // tot[b][0] = mask count
    }
#pragma unroll
    for (int off = 8; off > 0; off >>= 1) v += __shfl_down(v, off, 64);
    if (tid == 0) out[0] = (float)(v / (double)NB);
}

extern "C" void kernel_launch(void* const* d_in, const int* in_sizes, int n_in,
                              void* d_out, int out_size, void* d_ws, size_t ws_size,
                              hipStream_t stream) {
    const float* predictions = (const float*)d_in[0];
    const float* inputs      = (const float*)d_in[1];
    const int*   heart       = (const int*)d_in[2];
    float* out   = (float*)d_out;
    char*  wsraw = (char*)d_ws;

    pass1_moments<<<dim3(G1, NB), 256, 0, stream>>>(predictions, inputs, heart, wsraw);
    reduce_totals<<<dim3(NB),     256, 0, stream>>>(wsraw);
    pass2_loglik <<<dim3(G1, NB), 256, 0, stream>>>(predictions, inputs, heart, wsraw);
    finalize_kernel<<<1,          256, 0, stream>>>(wsraw, out);
}